// Round 7
// baseline (363.462 us; speedup 1.0000x reference)
//
#include <hip/hip_runtime.h>
#include <math.h>

#define BB 8
#define HH 640
#define WW 640
#define HWN (HH*WW)
#define CC 10
#define KCH 5
#define DD 4
#define LL 16
#define NBINS 256
#define ETILE 1024

// front kernel role split
#define NDIL   800                 // 8 batches x 100 (64x64) tiles
#define NDICEB 2048                // 8 batches x 256 x-chunks
// emb kernel grid (must ALL be co-resident for the barrier)
#define EGX    64
#define EGRID  (EGX * BB)          // 512 blocks

// ws layout (float offsets) — zeroed by memset each call
#define WS_OHEM      0                       // BB*8
#define WS_HCNT      64                      // BB*NBINS
#define WS_HS2       (WS_HCNT + BB*NBINS)    // BB*NBINS
#define WS_KERN      (WS_HS2 + BB*NBINS)     // 40*3
#define WS_ECNT      (WS_KERN + 120)         // BB*LL
#define WS_ESUM      (WS_ECNT + BB*LL)       // BB*LL*DD
#define WS_ECV       (WS_ESUM + BB*LL*DD)    // BB
#define WS_BAR       (WS_ECV + BB)           // 1 int (grid barrier)
#define WS_ZERO_END  (WS_BAR + 4)

typedef short bf16x8 __attribute__((ext_vector_type(8)));
typedef float f32x4  __attribute__((ext_vector_type(4)));

__device__ __forceinline__ float sigm(float x) { return 1.f / (1.f + __expf(-x)); }

__device__ __forceinline__ float wave_red(float v) {
    #pragma unroll
    for (int o = 32; o > 0; o >>= 1) v += __shfl_down(v, o);
    return v;
}

__device__ __forceinline__ unsigned short f2bf(float x) {
    return (unsigned short)((__float_as_uint(x) + 0x8000u) >> 16);
}

// Guarded float4 load of logit row; OOB -> -inf. cb is 4-aligned.
__device__ __forceinline__ float4 ld4g(const float* __restrict__ p, int row, int cb) {
    float4 v;
    if (row < 0 || row >= HH) { v.x = v.y = v.z = v.w = -INFINITY; return v; }
    const float* rp = p + (size_t)row * WW;
    if (cb >= 0 && cb <= WW - 4) return *(const float4*)(rp + cb);
    v.x = ((unsigned)(cb + 0) < (unsigned)WW) ? rp[cb + 0] : -INFINITY;
    v.y = ((unsigned)(cb + 1) < (unsigned)WW) ? rp[cb + 1] : -INFINITY;
    v.z = ((unsigned)(cb + 2) < (unsigned)WW) ? rp[cb + 2] : -INFINITY;
    v.w = ((unsigned)(cb + 3) < (unsigned)WW) ? rp[cb + 3] : -INFINITY;
    return v;
}

// Kernel 1 (fused front): role-partitioned.
//   blocks [0, NDIL):  9x9 max-dilation of pred[:,0] + OHEM stats + histogram
//   blocks [NDIL, NDIL+NDICEB): dice partial sums, all 5 kernel channels,
//     tm read once per pixel. Roles have similar VGPR (~80) and per-block work.
__global__ __launch_bounds__(256) void k_front(
    const float* __restrict__ pred, const float* __restrict__ gt_t,
    const float* __restrict__ gtk,  const float* __restrict__ tm,
    float* __restrict__ ws)
{
    __shared__ float smem[72 * 65 + 4 * NBINS + 8];   // 22.9 KB, dil worst case
    const int tid = threadIdx.x;
    const int blk = blockIdx.x;

    if (blk < NDIL) {
        float* hmax = smem;                   // [72][65]
        float* hcnt = smem + 72 * 65;         // [2][NBINS]
        float* hs2  = hcnt + 2 * NBINS;       // [2][NBINS]
        float* red  = hs2 + 2 * NBINS;        // [8]
        const int b   = blk / 100;
        const int rem = blk - b * 100;
        const int y0  = (rem / 10) * 64;
        const int x0  = (rem - (rem / 10) * 10) * 64;
        const float* p0 = pred + (size_t)b * CC * HWN;

        for (int i = tid; i < 4 * NBINS; i += 256) hcnt[i] = 0.f;
        if (tid < 8) red[tid] = 0.f;

        for (int i = tid; i < 72 * 16; i += 256) {
            int r = i >> 4, g = i & 15;
            int gr = y0 + r - 4;
            int cb = x0 + 4 * g - 4;
            float4 A  = ld4g(p0, gr, cb);
            float4 Bv = ld4g(p0, gr, cb + 4);
            float4 Cv = ld4g(p0, gr, cb + 8);
            float s3 = A.w;
            float s2 = fmaxf(A.z, s3);
            float s1 = fmaxf(A.y, s2);
            float s0 = fmaxf(A.x, s1);
            float mid = fmaxf(fmaxf(Bv.x, Bv.y), fmaxf(Bv.z, Bv.w));
            float q0 = Cv.x;
            float q1 = fmaxf(q0, Cv.y);
            float q2 = fmaxf(q1, Cv.z);
            float q3 = fmaxf(q2, Cv.w);
            int c = 4 * g;
            hmax[r * 65 + c + 0] = fmaxf(fmaxf(s0, mid), q0);
            hmax[r * 65 + c + 1] = fmaxf(fmaxf(s1, mid), q1);
            hmax[r * 65 + c + 2] = fmaxf(fmaxf(s2, mid), q2);
            hmax[r * 65 + c + 3] = fmaxf(fmaxf(s3, mid), q3);
        }
        __syncthreads();

        const int c  = tid & 63;
        const int rb = tid >> 6;
        const int hc = (tid >> 7) * NBINS;
        float c_pos = 0.f, s_pos = 0.f, s_pos2 = 0.f, c_neg = 0.f, s_neg2 = 0.f;
        #pragma unroll
        for (int k = 0; k < 16; k++) {
            int r = rb * 16 + k;
            float m = hmax[r * 65 + c];
            #pragma unroll
            for (int j = 1; j < 9; j++) m = fmaxf(m, hmax[(r + j) * 65 + c]);
            float dil = sigm(m);
            size_t gidx = (size_t)b * HWN + (size_t)(y0 + r) * WW + (x0 + c);
            float g = gt_t[gidx], mv = tm[gidx];
            if (mv > 0.5f) {
                if (g > 0.5f) { c_pos += 1.f; s_pos += dil; s_pos2 += dil * dil; }
                else {
                    c_neg += 1.f; s_neg2 += dil * dil;
                    int bin = (int)((m + 8.f) * 16.f);
                    bin = min(max(bin, 0), NBINS - 1);
                    atomicAdd(&hcnt[hc + bin], 1.f);
                    atomicAdd(&hs2[hc + bin], dil * dil);
                }
            }
        }
        c_pos = wave_red(c_pos); s_pos = wave_red(s_pos); s_pos2 = wave_red(s_pos2);
        c_neg = wave_red(c_neg); s_neg2 = wave_red(s_neg2);
        if ((tid & 63) == 0) {
            atomicAdd(&red[0], c_pos);  atomicAdd(&red[1], s_pos);
            atomicAdd(&red[2], s_pos2); atomicAdd(&red[3], c_neg);
            atomicAdd(&red[4], s_neg2);
        }
        __syncthreads();
        float* oh = ws + WS_OHEM + b * 8;
        if (tid < 5) atomicAdd(&oh[tid], red[tid]);
        float* gh_c = ws + WS_HCNT + b * NBINS;
        float* gh_s = ws + WS_HS2  + b * NBINS;
        for (int i = tid; i < NBINS; i += 256) {
            float sc = hcnt[i] + hcnt[NBINS + i];
            if (sc != 0.f) {
                atomicAdd(&gh_c[i], sc);
                atomicAdd(&gh_s[i], hs2[i] + hs2[NBINS + i]);
            }
        }
    } else {
        // ---------------- dice over all 5 channels ----------------
        const int d  = blk - NDIL;
        const int b  = d >> 8;          // / 256
        const int xb = d & 255;
        const float* pb = pred + ((size_t)b * CC + 1) * HWN;
        const float* gb = gtk + (size_t)b * KCH * HWN;
        const float4* m = (const float4*)(tm + (size_t)b * HWN);
        const int nv = HWN / 4;
        float i1[KCH], i2[KCH], i3[KCH];
        #pragma unroll
        for (int c = 0; c < KCH; c++) { i1[c] = 0.f; i2[c] = 0.f; i3[c] = 0.f; }

        for (int j = xb * 256 + tid; j < nv; j += 256 * 256) {
            float4 mv = m[j];
            #pragma unroll
            for (int c = 0; c < KCH; c++) {
                float4 pv = ((const float4*)(pb + (size_t)c * HWN))[j];
                float4 gv = ((const float4*)(gb + (size_t)c * HWN))[j];
                float s0 = sigm(pv.x), s1 = sigm(pv.y), s2 = sigm(pv.z), s3 = sigm(pv.w);
                i1[c] += s0*gv.x*mv.x + s1*gv.y*mv.y + s2*gv.z*mv.z + s3*gv.w*mv.w;
                i2[c] += s0*s0*mv.x + s1*s1*mv.y + s2*s2*mv.z + s3*s3*mv.w;
                i3[c] += gv.x*mv.x + gv.y*mv.y + gv.z*mv.z + gv.w*mv.w;
            }
        }

        float* sred = smem;   // [4][15]
        const int wv = tid >> 6;
        #pragma unroll
        for (int c = 0; c < KCH; c++) {
            float r1 = wave_red(i1[c]);
            float r2 = wave_red(i2[c]);
            float r3 = wave_red(i3[c]);
            if ((tid & 63) == 0) {
                sred[wv*15 + c*3+0] = r1; sred[wv*15 + c*3+1] = r2; sred[wv*15 + c*3+2] = r3;
            }
        }
        __syncthreads();
        if (tid < 15) {
            float s = sred[tid] + sred[15 + tid] + sred[30 + tid] + sred[45 + tid];
            int c = tid / 3, jj = tid - c * 3;
            atomicAdd(&ws[WS_KERN + (b * KCH + c) * 3 + jj], s);
        }
    }
}

// Kernel 2 (fused emb): phase A = emb1 MFMA label-sums; co-resident grid
// barrier; phase B = emb2 variance accumulation using global means.
// EGRID=512 blocks, __launch_bounds__(256,3) guarantees >=3 blocks/CU
// (capacity 768 >= 512) so the spin barrier cannot deadlock.
__global__ __launch_bounds__(256, 3) void k_emb(
    const float* __restrict__ pred, const int* __restrict__ inst,
    const float* __restrict__ tm, float* __restrict__ ws)
{
    const int b = blockIdx.y;
    __shared__ unsigned short chs[4][ETILE + 16];
    __shared__ unsigned int   labv[ETILE];
    __shared__ float          merge[4 * 80];
    const int tid  = threadIdx.x;
    const int wave = tid >> 6, lane = tid & 63;
    const int q = lane >> 4, n = lane & 15;
    const float* e0  = pred + ((size_t)b * CC + 6) * HWN;
    const float* tmb = tm + (size_t)b * HWN;
    const int*   ib  = inst + (size_t)b * HWN;

    const bool isch = (n >= 1 && n <= 4);
    const int  cn   = isch ? (n - 1) : 0;

    f32x4 acc = {0.f, 0.f, 0.f, 0.f};

    for (int t0 = blockIdx.x * ETILE; t0 < HWN; t0 += EGX * ETILE) {
        {
            int p = t0 + tid * 4;
            float4 T = *(const float4*)(tmb + p);
            int4   L = *(const int4*)(ib + p);
            #pragma unroll
            for (int c = 0; c < 4; c++) {
                float4 V = *(const float4*)(e0 + (size_t)c * HWN + p);
                unsigned short* dst = &chs[c][tid * 4];
                dst[0] = f2bf(V.x); dst[1] = f2bf(V.y);
                dst[2] = f2bf(V.z); dst[3] = f2bf(V.w);
            }
            uint4 lv;
            lv.x = (T.x > 0.f) ? (unsigned)L.x : 255u;
            lv.y = (T.y > 0.f) ? (unsigned)L.y : 255u;
            lv.z = (T.z > 0.f) ? (unsigned)L.z : 255u;
            lv.w = (T.w > 0.f) ? (unsigned)L.w : 255u;
            *(uint4*)&labv[tid * 4] = lv;
        }
        __syncthreads();

        for (int c2 = wave; c2 < ETILE / 32; c2 += 4) {
            const int base = c2 * 32 + q * 8;
            uint4 La = *(const uint4*)&labv[base];
            uint4 Lb = *(const uint4*)&labv[base + 4];
            union { unsigned short u[8]; bf16x8 v; } A_;
            const unsigned un = (unsigned)n;
            A_.u[0] = (La.x == un) ? 0x3F80 : 0;
            A_.u[1] = (La.y == un) ? 0x3F80 : 0;
            A_.u[2] = (La.z == un) ? 0x3F80 : 0;
            A_.u[3] = (La.w == un) ? 0x3F80 : 0;
            A_.u[4] = (Lb.x == un) ? 0x3F80 : 0;
            A_.u[5] = (Lb.y == un) ? 0x3F80 : 0;
            A_.u[6] = (Lb.z == un) ? 0x3F80 : 0;
            A_.u[7] = (Lb.w == un) ? 0x3F80 : 0;
            bf16x8 Bf;
            if (isch) {
                Bf = *(const bf16x8*)&chs[cn][base];
            } else if (n == 0) {
                #pragma unroll
                for (int j = 0; j < 8; j++) Bf[j] = (short)0x3F80;
            } else {
                #pragma unroll
                for (int j = 0; j < 8; j++) Bf[j] = 0;
            }
            acc = __builtin_amdgcn_mfma_f32_16x16x32_bf16(A_.v, Bf, acc, 0, 0, 0);
        }
        __syncthreads();
    }

    if (n <= 4) {
        #pragma unroll
        for (int r = 0; r < 4; r++)
            merge[wave * 80 + (q * 4 + r) * 5 + n] = acc[r];
    }
    __syncthreads();
    if (tid < 80) {
        float s = merge[tid] + merge[80 + tid] + merge[160 + tid] + merge[240 + tid];
        int l = tid / 5, c = tid - l * 5;
        if (c == 0) atomicAdd(&ws[WS_ECNT + b * LL + l], s);
        else        atomicAdd(&ws[WS_ESUM + b * LL * DD + l * DD + (c - 1)], s);
    }
    __syncthreads();

    // ---- grid barrier (single-use; counter zeroed by memset each call) ----
    int* bar = (int*)(ws + WS_BAR);
    if (tid == 0) {
        __threadfence();   // make this block's atomics visible device-wide
        __hip_atomic_fetch_add(bar, 1, __ATOMIC_ACQ_REL, __HIP_MEMORY_SCOPE_AGENT);
        while (__hip_atomic_load(bar, __ATOMIC_ACQUIRE, __HIP_MEMORY_SCOPE_AGENT) < EGRID) {
            __builtin_amdgcn_s_sleep(8);
        }
    }
    __syncthreads();

    // ---- phase B: means from ws (L2-hot), then variance accumulation ----
    __shared__ float mn[LL * DD];
    __shared__ float invc[LL];
    if (tid < LL) {
        float c = ws[WS_ECNT + b * LL + tid];
        invc[tid] = 1.f / fmaxf(c, 1.f);
    }
    __syncthreads();
    if (tid < LL * DD) {
        int l = tid >> 2;
        mn[tid] = ws[WS_ESUM + b * LL * DD + tid] * invc[l];
    }
    __syncthreads();

    const float4* v0p = (const float4*)e0;
    const float4* v1p = (const float4*)(e0 + HWN);
    const float4* v2p = (const float4*)(e0 + 2 * HWN);
    const float4* v3p = (const float4*)(e0 + 3 * HWN);
    const float4* tmv = (const float4*)tmb;
    const int4*   iv  = (const int4*)ib;

    float vacc = 0.f;
    const int nv = HWN / 4;
    for (int j = blockIdx.x * 256 + tid; j < nv; j += EGX * 256) {
        float4 a0 = v0p[j], a1 = v1p[j], a2 = v2p[j], a3 = v3p[j];
        float4 t = tmv[j];
        int4 li = iv[j];
        float ex[4] = {a0.x, a0.y, a0.z, a0.w};
        float ey[4] = {a1.x, a1.y, a1.z, a1.w};
        float ez[4] = {a2.x, a2.y, a2.z, a2.w};
        float ew[4] = {a3.x, a3.y, a3.z, a3.w};
        int   lb[4] = {li.x, li.y, li.z, li.w};
        float tv[4] = {t.x, t.y, t.z, t.w};
        #pragma unroll
        for (int qq = 0; qq < 4; qq++) {
            int l = lb[qq];                      // always in [0,16)
            float d0 = ex[qq] - mn[l * DD + 0];
            float d1 = ey[qq] - mn[l * DD + 1];
            float d2 = ez[qq] - mn[l * DD + 2];
            float d3 = ew[qq] - mn[l * DD + 3];
            float dd = sqrtf(d0*d0 + d1*d1 + d2*d2 + d3*d3 + 1e-12f);
            float tt = fmaxf(dd - 0.5f, 0.f);    // DELTA_V = 0.5
            float w = (tv[qq] > 0.f) ? invc[l] : 0.f;
            vacc += w * tt * tt;
        }
    }

    vacc = wave_red(vacc);
    __shared__ float sred[4];
    if ((tid & 63) == 0) sred[wave] = vacc;
    __syncthreads();
    if (tid == 0)
        atomicAdd(&ws[WS_ECV + b], sred[0] + sred[1] + sred[2] + sred[3]);
}

// Kernel 3: final combine → 4 scalars.
__global__ __launch_bounds__(256) void k_final(const float* __restrict__ ws, float* __restrict__ out)
{
    __shared__ float mn[BB][LL][DD];
    __shared__ float pres[BB][LL];
    __shared__ float nfa[BB], lda[BB], lra[BB];
    __shared__ float s_text[BB];
    __shared__ float s_kern[40];
    __shared__ float s_lv[BB], s_ld[BB], s_lr[BB];
    const int tid = threadIdx.x;
    if (tid < BB) { nfa[tid] = 0.f; lda[tid] = 0.f; lra[tid] = 0.f; }
    __syncthreads();
    if (tid < BB * LL) {
        int b = tid >> 4, l = tid & 15;
        float c = ws[WS_ECNT + b * LL + l];
        float inv = 1.f / fmaxf(c, 1.f);
        #pragma unroll
        for (int d = 0; d < DD; d++)
            mn[b][l][d] = ws[WS_ESUM + b * LL * DD + l * DD + d] * inv;
        float p = (c > 0.f) ? 1.f : 0.f;
        pres[b][l] = p;
        atomicAdd(&nfa[b], p);
    }
    __syncthreads();
    for (int t = tid; t < BB * 120; t += 256) {
        int b = t / 120, idx = t - b * 120, ii = 0;
        while (idx >= (LL - 1 - ii)) { idx -= (LL - 1 - ii); ii++; }
        int jj = ii + 1 + idx;
        if (pres[b][ii] > 0.f && pres[b][jj] > 0.f) {
            float s = 1e-12f;
            #pragma unroll
            for (int d = 0; d < DD; d++) {
                float df = mn[b][ii][d] - mn[b][jj][d]; s += df * df;
            }
            float tt = fmaxf(3.0f - sqrtf(s), 0.f);   // 2*DELTA_D
            if (tt > 0.f) atomicAdd(&lda[b], tt * tt);
        }
    }
    if (tid < BB * LL) {
        int b = tid >> 4, l = tid & 15;
        if (pres[b][l] > 0.f) {
            float s = 1e-12f;
            #pragma unroll
            for (int d = 0; d < DD; d++) s += mn[b][l][d] * mn[b][l][d];
            atomicAdd(&lra[b], sqrtf(s));
        }
    }
    __syncthreads();
    if (tid < BB) {
        const float* o = ws + WS_OHEM + tid * 8;
        float npos = o[0], spos = o[1], spos2 = o[2], nnegt = o[3], sneg2t = o[4];
        float nneg = fminf(3.f * npos, nnegt);
        float ssel;
        if (nneg >= nnegt) ssel = sneg2t;       // all negatives selected (exact path)
        else {
            const float* hcn = ws + WS_HCNT + tid * NBINS;
            const float* hs = ws + WS_HS2  + tid * NBINS;
            float acc = 0.f; ssel = 0.f;
            for (int i = NBINS - 1; i >= 0; i--) {
                float c = hcn[i];
                if (c <= 0.f) continue;
                if (acc + c <= nneg) { ssel += hs[i]; acc += c; }
                else { float r = nneg - acc; ssel += r * (hs[i] / c); break; }
            }
        }
        float uni = spos2 + ssel + npos + 1e-6f;
        s_text[tid] = 1.f - 2.f * spos / uni;

        float nf  = nfa[tid];
        float act = (nf > 1.f) ? 1.f : 0.f;
        s_lv[tid] = act * ws[WS_ECV + tid] / fmaxf(nf, 1.f);
        s_ld[tid] = act * lda[tid] / fmaxf(nf * (nf - 1.f), 1.f);
        s_lr[tid] = act * lra[tid] / fmaxf(nf, 1.f);
    }
    if (tid < 40) {
        const float* kk = ws + WS_KERN + tid * 3;
        s_kern[tid] = 1.f - 2.f * kk[0] / (kk[1] + kk[2] + 1e-6f);
    }
    __syncthreads();
    if (tid == 0) {
        float lt = 0.f; for (int i = 0; i < BB; i++) lt += s_text[i]; lt /= (float)BB;
        float lk = 0.f; for (int i = 0; i < 40; i++) lk += s_kern[i]; lk /= 40.f;
        float lvs = 0.f, lds_ = 0.f, lrs = 0.f;
        for (int i = 0; i < BB; i++) { lvs += s_lv[i]; lds_ += s_ld[i]; lrs += s_lr[i]; }
        float lemb = 0.25f * (lvs + lds_ + 0.001f * (lrs / (float)BB));
        out[0] = lk + 0.5f * lt + lemb;
        out[1] = lt;
        out[2] = lk;
        out[3] = lemb;
    }
}

extern "C" void kernel_launch(void* const* d_in, const int* in_sizes, int n_in,
                              void* d_out, int out_size, void* d_ws, size_t ws_size,
                              hipStream_t stream)
{
    (void)in_sizes; (void)n_in; (void)out_size; (void)ws_size;
    const float* pred = (const float*)d_in[0];
    const float* gt_t = (const float*)d_in[1];
    const float* gtk  = (const float*)d_in[2];
    const float* tm   = (const float*)d_in[3];
    const int*   inst = (const int*)d_in[4];
    float* out = (float*)d_out;
    float* ws  = (float*)d_ws;

    hipMemsetAsync(d_ws, 0, WS_ZERO_END * sizeof(float), stream);

    k_front<<<NDIL + NDICEB, 256, 0, stream>>>(pred, gt_t, gtk, tm, ws);
    k_emb<<<dim3(EGX, BB), 256, 0, stream>>>(pred, inst, tm, ws);
    k_final<<<1, 256, 0, stream>>>(ws, out);
}

// Round 8
// 311.623 us; speedup vs baseline: 1.1663x; 1.1663x over previous
//
#include <hip/hip_runtime.h>
#include <math.h>

#define BB 8
#define HH 640
#define WW 640
#define HWN (HH*WW)
#define CC 10
#define KCH 5
#define DD 4
#define LL 16
#define NBINS 256
#define ETILE 1024

// front kernel role split
#define NDIL   800                 // 8 batches x 100 (64x64) tiles
#define NDICEB 2048                // 8 batches x 256 x-chunks

// ws layout (float offsets) — zeroed by memset each call
#define WS_OHEM      0                       // BB*8
#define WS_HCNT      64                      // BB*NBINS
#define WS_HS2       (WS_HCNT + BB*NBINS)    // BB*NBINS
#define WS_KERN      (WS_HS2 + BB*NBINS)     // 40*3
#define WS_ECNT      (WS_KERN + 120)         // BB*LL
#define WS_ESUM      (WS_ECNT + BB*LL)       // BB*LL*DD
#define WS_ECV       (WS_ESUM + BB*LL*DD)    // BB
#define WS_ZERO_END  (WS_ECV + BB)

typedef short bf16x8 __attribute__((ext_vector_type(8)));
typedef float f32x4  __attribute__((ext_vector_type(4)));

__device__ __forceinline__ float sigm(float x) { return 1.f / (1.f + __expf(-x)); }

__device__ __forceinline__ float wave_red(float v) {
    #pragma unroll
    for (int o = 32; o > 0; o >>= 1) v += __shfl_down(v, o);
    return v;
}

__device__ __forceinline__ unsigned short f2bf(float x) {
    return (unsigned short)((__float_as_uint(x) + 0x8000u) >> 16);
}

// Guarded float4 load of logit row; OOB -> -inf. cb is 4-aligned.
__device__ __forceinline__ float4 ld4g(const float* __restrict__ p, int row, int cb) {
    float4 v;
    if (row < 0 || row >= HH) { v.x = v.y = v.z = v.w = -INFINITY; return v; }
    const float* rp = p + (size_t)row * WW;
    if (cb >= 0 && cb <= WW - 4) return *(const float4*)(rp + cb);
    v.x = ((unsigned)(cb + 0) < (unsigned)WW) ? rp[cb + 0] : -INFINITY;
    v.y = ((unsigned)(cb + 1) < (unsigned)WW) ? rp[cb + 1] : -INFINITY;
    v.z = ((unsigned)(cb + 2) < (unsigned)WW) ? rp[cb + 2] : -INFINITY;
    v.w = ((unsigned)(cb + 3) < (unsigned)WW) ? rp[cb + 3] : -INFINITY;
    return v;
}

// Kernel 1 (fused front): role-partitioned, resource-balanced.
//   blocks [0, NDIL):  9x9 max-dilation of pred[:,0] + OHEM stats + histogram
//   blocks [NDIL, ..): dice partial sums over all 5 kernel channels
__global__ __launch_bounds__(256) void k_front(
    const float* __restrict__ pred, const float* __restrict__ gt_t,
    const float* __restrict__ gtk,  const float* __restrict__ tm,
    float* __restrict__ ws)
{
    __shared__ float smem[72 * 65 + 4 * NBINS + 8];   // 22.9 KB, dil worst case
    const int tid = threadIdx.x;
    const int blk = blockIdx.x;

    if (blk < NDIL) {
        float* hmax = smem;                   // [72][65]
        float* hcnt = smem + 72 * 65;         // [2][NBINS]
        float* hs2  = hcnt + 2 * NBINS;       // [2][NBINS]
        float* red  = hs2 + 2 * NBINS;        // [8]
        const int b   = blk / 100;
        const int rem = blk - b * 100;
        const int y0  = (rem / 10) * 64;
        const int x0  = (rem - (rem / 10) * 10) * 64;
        const float* p0 = pred + (size_t)b * CC * HWN;

        for (int i = tid; i < 4 * NBINS; i += 256) hcnt[i] = 0.f;
        if (tid < 8) red[tid] = 0.f;

        for (int i = tid; i < 72 * 16; i += 256) {
            int r = i >> 4, g = i & 15;
            int gr = y0 + r - 4;
            int cb = x0 + 4 * g - 4;
            float4 A  = ld4g(p0, gr, cb);
            float4 Bv = ld4g(p0, gr, cb + 4);
            float4 Cv = ld4g(p0, gr, cb + 8);
            float s3 = A.w;
            float s2 = fmaxf(A.z, s3);
            float s1 = fmaxf(A.y, s2);
            float s0 = fmaxf(A.x, s1);
            float mid = fmaxf(fmaxf(Bv.x, Bv.y), fmaxf(Bv.z, Bv.w));
            float q0 = Cv.x;
            float q1 = fmaxf(q0, Cv.y);
            float q2 = fmaxf(q1, Cv.z);
            float q3 = fmaxf(q2, Cv.w);
            int c = 4 * g;
            hmax[r * 65 + c + 0] = fmaxf(fmaxf(s0, mid), q0);
            hmax[r * 65 + c + 1] = fmaxf(fmaxf(s1, mid), q1);
            hmax[r * 65 + c + 2] = fmaxf(fmaxf(s2, mid), q2);
            hmax[r * 65 + c + 3] = fmaxf(fmaxf(s3, mid), q3);
        }
        __syncthreads();

        const int c  = tid & 63;
        const int rb = tid >> 6;
        const int hc = (tid >> 7) * NBINS;
        float c_pos = 0.f, s_pos = 0.f, s_pos2 = 0.f, c_neg = 0.f, s_neg2 = 0.f;
        #pragma unroll
        for (int k = 0; k < 16; k++) {
            int r = rb * 16 + k;
            float m = hmax[r * 65 + c];
            #pragma unroll
            for (int j = 1; j < 9; j++) m = fmaxf(m, hmax[(r + j) * 65 + c]);
            float dil = sigm(m);
            size_t gidx = (size_t)b * HWN + (size_t)(y0 + r) * WW + (x0 + c);
            float g = gt_t[gidx], mv = tm[gidx];
            if (mv > 0.5f) {
                if (g > 0.5f) { c_pos += 1.f; s_pos += dil; s_pos2 += dil * dil; }
                else {
                    c_neg += 1.f; s_neg2 += dil * dil;
                    int bin = (int)((m + 8.f) * 16.f);
                    bin = min(max(bin, 0), NBINS - 1);
                    atomicAdd(&hcnt[hc + bin], 1.f);
                    atomicAdd(&hs2[hc + bin], dil * dil);
                }
            }
        }
        c_pos = wave_red(c_pos); s_pos = wave_red(s_pos); s_pos2 = wave_red(s_pos2);
        c_neg = wave_red(c_neg); s_neg2 = wave_red(s_neg2);
        if ((tid & 63) == 0) {
            atomicAdd(&red[0], c_pos);  atomicAdd(&red[1], s_pos);
            atomicAdd(&red[2], s_pos2); atomicAdd(&red[3], c_neg);
            atomicAdd(&red[4], s_neg2);
        }
        __syncthreads();
        float* oh = ws + WS_OHEM + b * 8;
        if (tid < 5) atomicAdd(&oh[tid], red[tid]);
        float* gh_c = ws + WS_HCNT + b * NBINS;
        float* gh_s = ws + WS_HS2  + b * NBINS;
        for (int i = tid; i < NBINS; i += 256) {
            float sc = hcnt[i] + hcnt[NBINS + i];
            if (sc != 0.f) {
                atomicAdd(&gh_c[i], sc);
                atomicAdd(&gh_s[i], hs2[i] + hs2[NBINS + i]);
            }
        }
    } else {
        // ---------------- dice over all 5 channels ----------------
        const int d  = blk - NDIL;
        const int b  = d >> 8;          // / 256
        const int xb = d & 255;
        const float* pb = pred + ((size_t)b * CC + 1) * HWN;
        const float* gb = gtk + (size_t)b * KCH * HWN;
        const float4* m = (const float4*)(tm + (size_t)b * HWN);
        const int nv = HWN / 4;
        float i1[KCH], i2[KCH], i3[KCH];
        #pragma unroll
        for (int c = 0; c < KCH; c++) { i1[c] = 0.f; i2[c] = 0.f; i3[c] = 0.f; }

        for (int j = xb * 256 + tid; j < nv; j += 256 * 256) {
            float4 mv = m[j];
            #pragma unroll
            for (int c = 0; c < KCH; c++) {
                float4 pv = ((const float4*)(pb + (size_t)c * HWN))[j];
                float4 gv = ((const float4*)(gb + (size_t)c * HWN))[j];
                float s0 = sigm(pv.x), s1 = sigm(pv.y), s2 = sigm(pv.z), s3 = sigm(pv.w);
                i1[c] += s0*gv.x*mv.x + s1*gv.y*mv.y + s2*gv.z*mv.z + s3*gv.w*mv.w;
                i2[c] += s0*s0*mv.x + s1*s1*mv.y + s2*s2*mv.z + s3*s3*mv.w;
                i3[c] += gv.x*mv.x + gv.y*mv.y + gv.z*mv.z + gv.w*mv.w;
            }
        }

        float* sred = smem;   // [4][15]
        const int wv = tid >> 6;
        #pragma unroll
        for (int c = 0; c < KCH; c++) {
            float r1 = wave_red(i1[c]);
            float r2 = wave_red(i2[c]);
            float r3 = wave_red(i3[c]);
            if ((tid & 63) == 0) {
                sred[wv*15 + c*3+0] = r1; sred[wv*15 + c*3+1] = r2; sred[wv*15 + c*3+2] = r3;
            }
        }
        __syncthreads();
        if (tid < 15) {
            float s = sred[tid] + sred[15 + tid] + sred[30 + tid] + sred[45 + tid];
            int c = tid / 3, jj = tid - c * 3;
            atomicAdd(&ws[WS_KERN + (b * KCH + c) * 3 + jj], s);
        }
    }
}

// Kernel 2: embedding pass 1 via MFMA (R6-proven structure).
__global__ __launch_bounds__(256) void k_emb1(
    const float* __restrict__ pred, const int* __restrict__ inst,
    const float* __restrict__ tm, float* __restrict__ ws)
{
    const int b = blockIdx.y;
    __shared__ unsigned short chs[4][ETILE + 16];
    __shared__ unsigned int   labv[ETILE];
    __shared__ float          merge[4 * 80];
    const int tid  = threadIdx.x;
    const int wave = tid >> 6, lane = tid & 63;
    const int q = lane >> 4, n = lane & 15;
    const float* e0  = pred + ((size_t)b * CC + 6) * HWN;
    const float* tmb = tm + (size_t)b * HWN;
    const int*   ib  = inst + (size_t)b * HWN;

    const bool isch = (n >= 1 && n <= 4);
    const int  cn   = isch ? (n - 1) : 0;

    f32x4 acc = {0.f, 0.f, 0.f, 0.f};

    for (int t0 = blockIdx.x * ETILE; t0 < HWN; t0 += gridDim.x * ETILE) {
        {
            int p = t0 + tid * 4;
            float4 T = *(const float4*)(tmb + p);
            int4   L = *(const int4*)(ib + p);
            #pragma unroll
            for (int c = 0; c < 4; c++) {
                float4 V = *(const float4*)(e0 + (size_t)c * HWN + p);
                unsigned short* dst = &chs[c][tid * 4];
                dst[0] = f2bf(V.x); dst[1] = f2bf(V.y);
                dst[2] = f2bf(V.z); dst[3] = f2bf(V.w);
            }
            uint4 lv;
            lv.x = (T.x > 0.f) ? (unsigned)L.x : 255u;
            lv.y = (T.y > 0.f) ? (unsigned)L.y : 255u;
            lv.z = (T.z > 0.f) ? (unsigned)L.z : 255u;
            lv.w = (T.w > 0.f) ? (unsigned)L.w : 255u;
            *(uint4*)&labv[tid * 4] = lv;
        }
        __syncthreads();

        for (int c2 = wave; c2 < ETILE / 32; c2 += 4) {
            const int base = c2 * 32 + q * 8;
            uint4 La = *(const uint4*)&labv[base];
            uint4 Lb = *(const uint4*)&labv[base + 4];
            union { unsigned short u[8]; bf16x8 v; } A_;
            const unsigned un = (unsigned)n;
            A_.u[0] = (La.x == un) ? 0x3F80 : 0;
            A_.u[1] = (La.y == un) ? 0x3F80 : 0;
            A_.u[2] = (La.z == un) ? 0x3F80 : 0;
            A_.u[3] = (La.w == un) ? 0x3F80 : 0;
            A_.u[4] = (Lb.x == un) ? 0x3F80 : 0;
            A_.u[5] = (Lb.y == un) ? 0x3F80 : 0;
            A_.u[6] = (Lb.z == un) ? 0x3F80 : 0;
            A_.u[7] = (Lb.w == un) ? 0x3F80 : 0;
            bf16x8 Bf;
            if (isch) {
                Bf = *(const bf16x8*)&chs[cn][base];
            } else if (n == 0) {
                #pragma unroll
                for (int j = 0; j < 8; j++) Bf[j] = (short)0x3F80;
            } else {
                #pragma unroll
                for (int j = 0; j < 8; j++) Bf[j] = 0;
            }
            acc = __builtin_amdgcn_mfma_f32_16x16x32_bf16(A_.v, Bf, acc, 0, 0, 0);
        }
        __syncthreads();
    }

    if (n <= 4) {
        #pragma unroll
        for (int r = 0; r < 4; r++)
            merge[wave * 80 + (q * 4 + r) * 5 + n] = acc[r];
    }
    __syncthreads();
    if (tid < 80) {
        float s = merge[tid] + merge[80 + tid] + merge[160 + tid] + merge[240 + tid];
        int l = tid / 5, c = tid - l * 5;
        if (c == 0) atomicAdd(&ws[WS_ECNT + b * LL + l], s);
        else        atomicAdd(&ws[WS_ESUM + b * LL * DD + l * DD + (c - 1)], s);
    }
}

// Kernel 3: embedding pass 2 — inline means/invc from ws, scalar accumulator.
__global__ __launch_bounds__(256) void k_emb2(
    const float* __restrict__ pred, const int* __restrict__ inst,
    const float* __restrict__ tm, float* __restrict__ ws)
{
    const int b = blockIdx.y;
    const int tid = threadIdx.x;
    __shared__ float mn[LL * DD];
    __shared__ float invc[LL];
    if (tid < LL) {
        float c = ws[WS_ECNT + b * LL + tid];
        invc[tid] = 1.f / fmaxf(c, 1.f);
    }
    __syncthreads();
    if (tid < LL * DD) {
        int l = tid >> 2;
        mn[tid] = ws[WS_ESUM + b * LL * DD + tid] * invc[l];
    }
    __syncthreads();

    const float* e0 = pred + ((size_t)b * CC + 6) * HWN;
    const float4* v0p = (const float4*)e0;
    const float4* v1p = (const float4*)(e0 + HWN);
    const float4* v2p = (const float4*)(e0 + 2 * HWN);
    const float4* v3p = (const float4*)(e0 + 3 * HWN);
    const float4* tmv = (const float4*)(tm + (size_t)b * HWN);
    const int4*   iv  = (const int4*)(inst + (size_t)b * HWN);

    float acc = 0.f;
    const int nv = HWN / 4;
    for (int j = blockIdx.x * 256 + tid; j < nv; j += gridDim.x * 256) {
        float4 a0 = v0p[j], a1 = v1p[j], a2 = v2p[j], a3 = v3p[j];
        float4 t = tmv[j];
        int4 li = iv[j];
        float ex[4] = {a0.x, a0.y, a0.z, a0.w};
        float ey[4] = {a1.x, a1.y, a1.z, a1.w};
        float ez[4] = {a2.x, a2.y, a2.z, a2.w};
        float ew[4] = {a3.x, a3.y, a3.z, a3.w};
        int   lb[4] = {li.x, li.y, li.z, li.w};
        float tv[4] = {t.x, t.y, t.z, t.w};
        #pragma unroll
        for (int qq = 0; qq < 4; qq++) {
            int l = lb[qq];                      // always in [0,16)
            float d0 = ex[qq] - mn[l * DD + 0];
            float d1 = ey[qq] - mn[l * DD + 1];
            float d2 = ez[qq] - mn[l * DD + 2];
            float d3 = ew[qq] - mn[l * DD + 3];
            float dd = sqrtf(d0*d0 + d1*d1 + d2*d2 + d3*d3 + 1e-12f);
            float tt = fmaxf(dd - 0.5f, 0.f);    // DELTA_V = 0.5
            float w = (tv[qq] > 0.f) ? invc[l] : 0.f;
            acc += w * tt * tt;
        }
    }

    acc = wave_red(acc);
    __shared__ float sred[4];
    const int wv = tid >> 6;
    if ((tid & 63) == 0) sred[wv] = acc;
    __syncthreads();
    if (tid == 0)
        atomicAdd(&ws[WS_ECV + b], sred[0] + sred[1] + sred[2] + sred[3]);
}

// Kernel 4: final combine → 4 scalars.
__global__ __launch_bounds__(256) void k_final(const float* __restrict__ ws, float* __restrict__ out)
{
    __shared__ float mn[BB][LL][DD];
    __shared__ float pres[BB][LL];
    __shared__ float nfa[BB], lda[BB], lra[BB];
    __shared__ float s_text[BB];
    __shared__ float s_kern[40];
    __shared__ float s_lv[BB], s_ld[BB], s_lr[BB];
    const int tid = threadIdx.x;
    if (tid < BB) { nfa[tid] = 0.f; lda[tid] = 0.f; lra[tid] = 0.f; }
    __syncthreads();
    if (tid < BB * LL) {
        int b = tid >> 4, l = tid & 15;
        float c = ws[WS_ECNT + b * LL + l];
        float inv = 1.f / fmaxf(c, 1.f);
        #pragma unroll
        for (int d = 0; d < DD; d++)
            mn[b][l][d] = ws[WS_ESUM + b * LL * DD + l * DD + d] * inv;
        float p = (c > 0.f) ? 1.f : 0.f;
        pres[b][l] = p;
        atomicAdd(&nfa[b], p);
    }
    __syncthreads();
    for (int t = tid; t < BB * 120; t += 256) {
        int b = t / 120, idx = t - b * 120, ii = 0;
        while (idx >= (LL - 1 - ii)) { idx -= (LL - 1 - ii); ii++; }
        int jj = ii + 1 + idx;
        if (pres[b][ii] > 0.f && pres[b][jj] > 0.f) {
            float s = 1e-12f;
            #pragma unroll
            for (int d = 0; d < DD; d++) {
                float df = mn[b][ii][d] - mn[b][jj][d]; s += df * df;
            }
            float tt = fmaxf(3.0f - sqrtf(s), 0.f);   // 2*DELTA_D
            if (tt > 0.f) atomicAdd(&lda[b], tt * tt);
        }
    }
    if (tid < BB * LL) {
        int b = tid >> 4, l = tid & 15;
        if (pres[b][l] > 0.f) {
            float s = 1e-12f;
            #pragma unroll
            for (int d = 0; d < DD; d++) s += mn[b][l][d] * mn[b][l][d];
            atomicAdd(&lra[b], sqrtf(s));
        }
    }
    __syncthreads();
    if (tid < BB) {
        const float* o = ws + WS_OHEM + tid * 8;
        float npos = o[0], spos = o[1], spos2 = o[2], nnegt = o[3], sneg2t = o[4];
        float nneg = fminf(3.f * npos, nnegt);
        float ssel;
        if (nneg >= nnegt) ssel = sneg2t;       // all negatives selected (exact path)
        else {
            const float* hcn = ws + WS_HCNT + tid * NBINS;
            const float* hs = ws + WS_HS2  + tid * NBINS;
            float acc = 0.f; ssel = 0.f;
            for (int i = NBINS - 1; i >= 0; i--) {
                float c = hcn[i];
                if (c <= 0.f) continue;
                if (acc + c <= nneg) { ssel += hs[i]; acc += c; }
                else { float r = nneg - acc; ssel += r * (hs[i] / c); break; }
            }
        }
        float uni = spos2 + ssel + npos + 1e-6f;
        s_text[tid] = 1.f - 2.f * spos / uni;

        float nf  = nfa[tid];
        float act = (nf > 1.f) ? 1.f : 0.f;
        s_lv[tid] = act * ws[WS_ECV + tid] / fmaxf(nf, 1.f);
        s_ld[tid] = act * lda[tid] / fmaxf(nf * (nf - 1.f), 1.f);
        s_lr[tid] = act * lra[tid] / fmaxf(nf, 1.f);
    }
    if (tid < 40) {
        const float* kk = ws + WS_KERN + tid * 3;
        s_kern[tid] = 1.f - 2.f * kk[0] / (kk[1] + kk[2] + 1e-6f);
    }
    __syncthreads();
    if (tid == 0) {
        float lt = 0.f; for (int i = 0; i < BB; i++) lt += s_text[i]; lt /= (float)BB;
        float lk = 0.f; for (int i = 0; i < 40; i++) lk += s_kern[i]; lk /= 40.f;
        float lvs = 0.f, lds_ = 0.f, lrs = 0.f;
        for (int i = 0; i < BB; i++) { lvs += s_lv[i]; lds_ += s_ld[i]; lrs += s_lr[i]; }
        float lemb = 0.25f * (lvs + lds_ + 0.001f * (lrs / (float)BB));
        out[0] = lk + 0.5f * lt + lemb;
        out[1] = lt;
        out[2] = lk;
        out[3] = lemb;
    }
}

extern "C" void kernel_launch(void* const* d_in, const int* in_sizes, int n_in,
                              void* d_out, int out_size, void* d_ws, size_t ws_size,
                              hipStream_t stream)
{
    (void)in_sizes; (void)n_in; (void)out_size; (void)ws_size;
    const float* pred = (const float*)d_in[0];
    const float* gt_t = (const float*)d_in[1];
    const float* gtk  = (const float*)d_in[2];
    const float* tm   = (const float*)d_in[3];
    const int*   inst = (const int*)d_in[4];
    float* out = (float*)d_out;
    float* ws  = (float*)d_ws;

    hipMemsetAsync(d_ws, 0, WS_ZERO_END * sizeof(float), stream);

    k_front<<<NDIL + NDICEB, 256, 0, stream>>>(pred, gt_t, gtk, tm, ws);
    k_emb1<<<dim3(100, BB), 256, 0, stream>>>(pred, inst, tm, ws);
    k_emb2<<<dim3(160, BB), 256, 0, stream>>>(pred, inst, tm, ws);
    k_final<<<1, 256, 0, stream>>>(ws, out);
}